// Round 10
// baseline (191.064 us; speedup 1.0000x reference)
//
#include <hip/hip_runtime.h>
#include <hip/hip_bf16.h>

#define WL_CAP 65536u

typedef __attribute__((ext_vector_type(4))) int i32x4;
typedef __attribute__((ext_vector_type(4))) float f32x4v;
typedef __attribute__((ext_vector_type(4))) unsigned short u16x4v;

// ---------------- zero the worklist counter (replaces hipMemsetAsync) -------------
__global__ void zero_counter(unsigned* c) { if (threadIdx.x == 0) *c = 0; }

// ---------------- Diagnostic probes: 384 MB each, visible in top-5 ONLY if slow ----
// probe_x_read: 3 NT sweeps of x (384 MB read), per-thread sum to sink.
__global__ __launch_bounds__(256) void probe_x_read(const float* __restrict__ x,
                                                    float* __restrict__ sink) {
  int tid = blockIdx.x * 256 + threadIdx.x;     // 2048 blocks = 524288 threads
  float acc = 0.f;
  for (int pass = 0; pass < 3; ++pass) {
#pragma unroll
    for (int k = 0; k < 16; ++k) {
      size_t i = (size_t)(tid + k * 524288) * 4;
      f32x4v v = __builtin_nontemporal_load(reinterpret_cast<const f32x4v*>(x + i));
      acc += v.x + v.y + v.z + v.w;
    }
    asm volatile("" ::: "memory");
  }
  sink[tid] = acc;
}

// probe_out_write: 3 NT fills of out (384 MB write). spike later overwrites all of out.
__global__ __launch_bounds__(256) void probe_out_write(float* __restrict__ out) {
  int tid = blockIdx.x * 256 + threadIdx.x;
  f32x4v v; v.x = 0.25f; v.y = 0.25f; v.z = 0.25f; v.w = 0.25f;
  for (int pass = 0; pass < 3; ++pass) {
#pragma unroll
    for (int k = 0; k < 16; ++k) {
      size_t i = (size_t)(tid + ((k + pass) & 15) * 524288) * 4;
      __builtin_nontemporal_store(v, reinterpret_cast<f32x4v*>(out + i));
    }
    asm volatile("" ::: "memory");
  }
}

// probe_ws_copy: 3x 64MB ws->ws copy (384 MB traffic). Control: is d_ws fast for US?
__global__ __launch_bounds__(256) void probe_ws_copy(const float* __restrict__ src,
                                                     float* __restrict__ dst) {
  int tid = blockIdx.x * 256 + threadIdx.x;
  for (int pass = 0; pass < 3; ++pass) {
#pragma unroll
    for (int k = 0; k < 8; ++k) {
      size_t i = (size_t)(tid + k * 524288) * 4;
      f32x4v v = __builtin_nontemporal_load(reinterpret_cast<const f32x4v*>(src + i));
      __builtin_nontemporal_store(v, reinterpret_cast<f32x4v*>(dst + i));
    }
    asm volatile("" ::: "memory");
  }
}

// ---------------- Kernel P: wsum_i8[o][c] = clamp(rint((w1+w2)*256), -127, 127) ----
__global__ void prep_wsum_i8(const float* __restrict__ w1, const float* __restrict__ w2,
                             char* __restrict__ wsum) {
  int i = (blockIdx.x * 256 + threadIdx.x) * 4;   // 256 blocks: 262144 elems
  float4 a = *reinterpret_cast<const float4*>(w1 + i);
  float4 b = *reinterpret_cast<const float4*>(w2 + i);
  int v0 = __float2int_rn(fminf(fmaxf((a.x + b.x) * 256.f, -127.f), 127.f));
  int v1 = __float2int_rn(fminf(fmaxf((a.y + b.y) * 256.f, -127.f), 127.f));
  int v2 = __float2int_rn(fminf(fmaxf((a.z + b.z) * 256.f, -127.f), 127.f));
  int v3 = __float2int_rn(fminf(fmaxf((a.w + b.w) * 256.f, -127.f), 127.f));
  unsigned u = (v0 & 0xFF) | ((v1 & 0xFF) << 8) | ((v2 & 0xFF) << 16) | ((v3 & 0xFF) << 24);
  *reinterpret_cast<unsigned*>(wsum + i) = u;
}

// ---- Kernel E (R5 best-known): batched loads then stores. Block = (b, cg of 16 ch).
__global__ __launch_bounds__(256) void spike_pack_direct(const float* __restrict__ x,
                                                         float* __restrict__ out,
                                                         unsigned short* __restrict__ xinb16) {
  int t = threadIdx.x;
  int g = blockIdx.x;              // 2048 = 64 b * 32 cg
  int b = g >> 5, cg = g & 31;
  int px = t * 4;
  size_t rowbase = ((size_t)(b * 512 + cg * 16)) * 1024 + (size_t)px;

  f32x4v v[16];
#pragma unroll
  for (int ci = 0; ci < 16; ++ci)
    v[ci] = *reinterpret_cast<const f32x4v*>(x + rowbase + (size_t)ci * 1024);

  unsigned u0 = 0, u1 = 0, u2 = 0, u3 = 0;
#pragma unroll
  for (int ci = 0; ci < 16; ++ci) {
    unsigned s0 = (v[ci].x >= 1.f) ? 1u : 0u;
    unsigned s1 = (v[ci].y >= 1.f) ? 1u : 0u;
    unsigned s2 = (v[ci].z >= 1.f) ? 1u : 0u;
    unsigned s3 = (v[ci].w >= 1.f) ? 1u : 0u;
    f32x4v ov;
    ov.x = 0.5f * (float)s0; ov.y = 0.5f * (float)s1;
    ov.z = 0.5f * (float)s2; ov.w = 0.5f * (float)s3;
    *reinterpret_cast<f32x4v*>(out + rowbase + (size_t)ci * 1024) = ov;
    u0 |= s0 << ci; u1 |= s1 << ci; u2 |= s2 << ci; u3 |= s3 << ci;
  }
  u16x4v o;
  o.x = (unsigned short)u0; o.y = (unsigned short)u1;
  o.z = (unsigned short)u2; o.w = (unsigned short)u3;
  *reinterpret_cast<u16x4v*>(xinb16 + (size_t)cg * 65536 + (size_t)(b * 1024 + px)) = o;
}

// ---- Kernel G (R5): i8 fire-detect GEMM, bbits preloaded from bitplanes ----------
__global__ __launch_bounds__(256) void gemm_fire_i8(const char* __restrict__ wsum,
                                                    const unsigned short* __restrict__ xinb16,
                                                    unsigned* __restrict__ counter,
                                                    unsigned* __restrict__ wl) {
  __shared__ char As[128 * 512];   // 64 KB
  int m0 = blockIdx.x * 128;
  int n0 = blockIdx.y * 128;
  int t = threadIdx.x;
  int lane = t & 63;
  int wv = t >> 6;
  int wr = wv >> 1, wc = wv & 1;
  int fr = lane & 15;
  int kgrp = lane >> 4;

#pragma unroll
  for (int i = 0; i < 16; ++i) {
    int idx = t + i * 256;
    int row = idx >> 5;
    int col16 = (idx & 31) * 16;
    int scol = col16 ^ ((row & 7) << 4);
    const char* ga = wsum + (size_t)(m0 + row) * 512 + scol;
    __builtin_amdgcn_global_load_lds((const __attribute__((address_space(1))) void*)ga,
                                     (__attribute__((address_space(3))) void*)(As + idx * 16),
                                     16, 0, 0);
  }

  unsigned short bbits[4][8];
#pragma unroll
  for (int ni = 0; ni < 4; ++ni) {
    int prow = n0 + wc * 64 + ni * 16 + fr;
#pragma unroll
    for (int kt = 0; kt < 8; ++kt)
      bbits[ni][kt] = xinb16[(size_t)(kt * 4 + kgrp) * 65536 + prow];
  }

  i32x4 acc[4][4];
#pragma unroll
  for (int i = 0; i < 4; ++i)
#pragma unroll
    for (int j = 0; j < 4; ++j) acc[i][j] = (i32x4){0, 0, 0, 0};

  __syncthreads();

#pragma unroll
  for (int kt = 0; kt < 8; ++kt) {
    i32x4 av[4];
#pragma unroll
    for (int mi = 0; mi < 4; ++mi) {
      int row = wr * 64 + mi * 16 + fr;
      int col = (kt * 64 + kgrp * 16) ^ ((row & 7) << 4);
      av[mi] = *reinterpret_cast<const i32x4*>(&As[row * 512 + col]);
    }
#pragma unroll
    for (int ni = 0; ni < 4; ++ni) {
      unsigned s = bbits[ni][kt];
      i32x4 bv;
      bv[0] = (int)((((s      ) & 0xFu) * 0x00204081u) & 0x01010101u);
      bv[1] = (int)((((s >>  4) & 0xFu) * 0x00204081u) & 0x01010101u);
      bv[2] = (int)((((s >>  8) & 0xFu) * 0x00204081u) & 0x01010101u);
      bv[3] = (int)((((s >> 12) & 0xFu) * 0x00204081u) & 0x01010101u);
#pragma unroll
      for (int mi = 0; mi < 4; ++mi)
        acc[mi][ni] = __builtin_amdgcn_mfma_i32_16x16x64_i8(av[mi], bv, acc[mi][ni], 0, 0, 0);
    }
  }

  int rowg = (lane >> 4) * 4;
#pragma unroll
  for (int mi = 0; mi < 4; ++mi)
#pragma unroll
    for (int ni = 0; ni < 4; ++ni)
#pragma unroll
      for (int v = 0; v < 4; ++v) {
        if (acc[mi][ni][v] >= 896) {
          unsigned o = (unsigned)(m0 + wr * 64 + mi * 16 + rowg + v);
          unsigned p = (unsigned)(n0 + wc * 64 + ni * 16 + fr);
          unsigned slot = atomicAdd(counter, 1u);
          if (slot < WL_CAP) wl[slot] = (o << 16) | p;
        }
      }
}

// ---- Kernel W: exact fp32 recheck (sieve AND source); scatter 0.5*w_lin[:,o] -------
__global__ void finish_fires(const float* __restrict__ x, const float* __restrict__ w1,
                             const float* __restrict__ w2, const float* __restrict__ wsrc,
                             const float* __restrict__ wlin, float* __restrict__ out,
                             const unsigned* __restrict__ counter,
                             const unsigned* __restrict__ wl) {
  unsigned n = *counter;
  if (n > WL_CAP) n = WL_CAP;
  for (unsigned i = blockIdx.x * blockDim.x + threadIdx.x; i < n;
       i += gridDim.x * blockDim.x) {
    unsigned e = wl[i];
    int o = (int)(e >> 16);
    int p = (int)(e & 0xFFFFu);
    int b = p >> 10, hw = p & 1023;
    const float* xb = x + (size_t)b * 512 * 1024 + hw;
    float s1 = 0.f, s2 = 0.f;
    for (int c = 0; c < 512; ++c) {
      if (xb[(size_t)c * 1024] >= 1.f) {
        s1 += w1[o * 512 + c] + w2[o * 512 + c];
        s2 += wsrc[o * 512 + c];
      }
    }
    if (s1 >= 4.0f && s2 >= 1.0f) {
      for (int c = 0; c < 512; ++c)
        atomicAdd(&out[((size_t)b * 512 + c) * 1024 + hw], 0.5f * wlin[c * 512 + o]);
    }
  }
}

// ---- Fallback (tiny workspace): dense fp32, one pixel per block, no scratch ------
__global__ void fallback_dense(const float* __restrict__ x, const float* __restrict__ w1,
                               const float* __restrict__ w2, const float* __restrict__ wsrc,
                               const float* __restrict__ wlin, float* __restrict__ out) {
  __shared__ float xin[512];
  __shared__ float gated[512];
  int p = blockIdx.x;
  int b = p >> 10, hw = p & 1023;
  const float* xb = x + (size_t)b * 512 * 1024 + hw;
  for (int c = threadIdx.x; c < 512; c += 256)
    xin[c] = (xb[(size_t)c * 1024] >= 1.f) ? 1.f : 0.f;
  __syncthreads();
  for (int o = threadIdx.x; o < 512; o += 256) {
    float s1 = 0.f, s2 = 0.f;
    for (int c = 0; c < 512; ++c) {
      float xv = xin[c];
      s1 += xv * (w1[o * 512 + c] + w2[o * 512 + c]);
      s2 += xv * wsrc[o * 512 + c];
    }
    gated[o] = (s1 >= 4.f && s2 >= 1.f) ? 1.f : 0.f;
  }
  __syncthreads();
  for (int c = threadIdx.x; c < 512; c += 256) {
    float a = 0.f;
    for (int o = 0; o < 512; ++o) a += gated[o] * wlin[c * 512 + o];
    out[((size_t)b * 512 + c) * 1024 + hw] = 0.5f * (a + xin[c]);
  }
}

extern "C" void kernel_launch(void* const* d_in, const int* in_sizes, int n_in,
                              void* d_out, int out_size, void* d_ws, size_t ws_size,
                              hipStream_t stream) {
  const float* x    = (const float*)d_in[0];
  const float* w1   = (const float*)d_in[1];
  const float* w2   = (const float*)d_in[2];
  const float* wsrc = (const float*)d_in[3];
  const float* wlin = (const float*)d_in[4];
  float* out = (float*)d_out;

  if (ws_size >= (size_t)8 * 1024 * 1024) {
    unsigned* counter = (unsigned*)d_ws;
    unsigned* wl = (unsigned*)((char*)d_ws + 1024);
    char* wsum_i8 = (char*)d_ws + (1u << 20);
    unsigned short* xinb16 = (unsigned short*)((char*)d_ws + (2u << 20));  // 4 MB planes
    float* sink = (float*)((char*)d_ws + (6u << 20));                      // 2 MB

    // --- Diagnostic probes (before real pipeline; out re-written by spike) ---
    if (ws_size >= (size_t)160 * 1024 * 1024) {
      float* psrc = (float*)((char*)d_ws + (size_t)(32u) * 1024 * 1024);   // 64 MB
      float* pdst = (float*)((char*)d_ws + (size_t)(96u) * 1024 * 1024);   // 64 MB
      probe_x_read<<<2048, 256, 0, stream>>>(x, sink);
      probe_out_write<<<2048, 256, 0, stream>>>(out);
      probe_ws_copy<<<2048, 256, 0, stream>>>(psrc, pdst);
    }

    zero_counter<<<1, 64, 0, stream>>>(counter);
    prep_wsum_i8<<<256, 256, 0, stream>>>(w1, w2, wsum_i8);
    spike_pack_direct<<<2048, 256, 0, stream>>>(x, out, xinb16);
    gemm_fire_i8<<<dim3(4, 512), 256, 0, stream>>>(wsum_i8, xinb16, counter, wl);
    finish_fires<<<dim3(32), 64, 0, stream>>>(x, w1, w2, wsrc, wlin, out, counter, wl);
  } else {
    fallback_dense<<<65536, 256, 0, stream>>>(x, w1, w2, wsrc, wlin, out);
  }
}

// Round 11
// 82.013 us; speedup vs baseline: 2.3297x; 2.3297x over previous
//
#include <hip/hip_runtime.h>
#include <hip/hip_bf16.h>

#define WL_CAP 65536u

typedef __attribute__((ext_vector_type(4))) int i32x4;
typedef __attribute__((ext_vector_type(4))) float f32x4v;
typedef __attribute__((ext_vector_type(4))) unsigned short u16x4v;

// ---------------- zero the worklist counter -----------------------------------------
__global__ void zero_counter(unsigned* c) { if (threadIdx.x == 0) *c = 0; }

// ---------------- Kernel P: wsum_i8[o][c] = clamp(rint((w1+w2)*256), -127, 127) ----
__global__ void prep_wsum_i8(const float* __restrict__ w1, const float* __restrict__ w2,
                             char* __restrict__ wsum) {
  int i = (blockIdx.x * 256 + threadIdx.x) * 4;   // 256 blocks: 262144 elems
  float4 a = *reinterpret_cast<const float4*>(w1 + i);
  float4 b = *reinterpret_cast<const float4*>(w2 + i);
  int v0 = __float2int_rn(fminf(fmaxf((a.x + b.x) * 256.f, -127.f), 127.f));
  int v1 = __float2int_rn(fminf(fmaxf((a.y + b.y) * 256.f, -127.f), 127.f));
  int v2 = __float2int_rn(fminf(fmaxf((a.z + b.z) * 256.f, -127.f), 127.f));
  int v3 = __float2int_rn(fminf(fmaxf((a.w + b.w) * 256.f, -127.f), 127.f));
  unsigned u = (v0 & 0xFF) | ((v1 & 0xFF) << 8) | ((v2 & 0xFF) << 16) | ((v3 & 0xFF) << 24);
  *reinterpret_cast<unsigned*>(wsum + i) = u;
}

// ---- Kernel E (R5 structure + NONTEMPORAL big streams). Block = (b, cg of 16 ch).
// Thread = 4 consecutive pixels. NT loads of x (no L3 alloc), NT stores of out
// (no write-allocate churn). Bitmask store regular (re-read by gemm, 4 MB total).
__global__ __launch_bounds__(256) void spike_pack_direct(const float* __restrict__ x,
                                                         float* __restrict__ out,
                                                         unsigned short* __restrict__ xinb16) {
  int t = threadIdx.x;
  int g = blockIdx.x;              // 2048 = 64 b * 32 cg
  int b = g >> 5, cg = g & 31;
  int px = t * 4;
  size_t rowbase = ((size_t)(b * 512 + cg * 16)) * 1024 + (size_t)px;

  f32x4v v[16];
#pragma unroll
  for (int ci = 0; ci < 16; ++ci)
    v[ci] = __builtin_nontemporal_load(
        reinterpret_cast<const f32x4v*>(x + rowbase + (size_t)ci * 1024));

  unsigned u0 = 0, u1 = 0, u2 = 0, u3 = 0;
#pragma unroll
  for (int ci = 0; ci < 16; ++ci) {
    unsigned s0 = (v[ci].x >= 1.f) ? 1u : 0u;
    unsigned s1 = (v[ci].y >= 1.f) ? 1u : 0u;
    unsigned s2 = (v[ci].z >= 1.f) ? 1u : 0u;
    unsigned s3 = (v[ci].w >= 1.f) ? 1u : 0u;
    f32x4v ov;
    ov.x = 0.5f * (float)s0; ov.y = 0.5f * (float)s1;
    ov.z = 0.5f * (float)s2; ov.w = 0.5f * (float)s3;
    __builtin_nontemporal_store(ov,
        reinterpret_cast<f32x4v*>(out + rowbase + (size_t)ci * 1024));
    u0 |= s0 << ci; u1 |= s1 << ci; u2 |= s2 << ci; u3 |= s3 << ci;
  }
  u16x4v o;
  o.x = (unsigned short)u0; o.y = (unsigned short)u1;
  o.z = (unsigned short)u2; o.w = (unsigned short)u3;
  *reinterpret_cast<u16x4v*>(xinb16 + (size_t)cg * 65536 + (size_t)(b * 1024 + px)) = o;
}

// ---- Kernel G (R5): i8 fire-detect GEMM, bbits preloaded from bitplanes ----------
__global__ __launch_bounds__(256) void gemm_fire_i8(const char* __restrict__ wsum,
                                                    const unsigned short* __restrict__ xinb16,
                                                    unsigned* __restrict__ counter,
                                                    unsigned* __restrict__ wl) {
  __shared__ char As[128 * 512];   // 64 KB
  int m0 = blockIdx.x * 128;
  int n0 = blockIdx.y * 128;
  int t = threadIdx.x;
  int lane = t & 63;
  int wv = t >> 6;
  int wr = wv >> 1, wc = wv & 1;
  int fr = lane & 15;
  int kgrp = lane >> 4;

#pragma unroll
  for (int i = 0; i < 16; ++i) {
    int idx = t + i * 256;
    int row = idx >> 5;
    int col16 = (idx & 31) * 16;
    int scol = col16 ^ ((row & 7) << 4);
    const char* ga = wsum + (size_t)(m0 + row) * 512 + scol;
    __builtin_amdgcn_global_load_lds((const __attribute__((address_space(1))) void*)ga,
                                     (__attribute__((address_space(3))) void*)(As + idx * 16),
                                     16, 0, 0);
  }

  unsigned short bbits[4][8];
#pragma unroll
  for (int ni = 0; ni < 4; ++ni) {
    int prow = n0 + wc * 64 + ni * 16 + fr;
#pragma unroll
    for (int kt = 0; kt < 8; ++kt)
      bbits[ni][kt] = xinb16[(size_t)(kt * 4 + kgrp) * 65536 + prow];
  }

  i32x4 acc[4][4];
#pragma unroll
  for (int i = 0; i < 4; ++i)
#pragma unroll
    for (int j = 0; j < 4; ++j) acc[i][j] = (i32x4){0, 0, 0, 0};

  __syncthreads();

#pragma unroll
  for (int kt = 0; kt < 8; ++kt) {
    i32x4 av[4];
#pragma unroll
    for (int mi = 0; mi < 4; ++mi) {
      int row = wr * 64 + mi * 16 + fr;
      int col = (kt * 64 + kgrp * 16) ^ ((row & 7) << 4);
      av[mi] = *reinterpret_cast<const i32x4*>(&As[row * 512 + col]);
    }
#pragma unroll
    for (int ni = 0; ni < 4; ++ni) {
      unsigned s = bbits[ni][kt];
      i32x4 bv;
      bv[0] = (int)((((s      ) & 0xFu) * 0x00204081u) & 0x01010101u);
      bv[1] = (int)((((s >>  4) & 0xFu) * 0x00204081u) & 0x01010101u);
      bv[2] = (int)((((s >>  8) & 0xFu) * 0x00204081u) & 0x01010101u);
      bv[3] = (int)((((s >> 12) & 0xFu) * 0x00204081u) & 0x01010101u);
#pragma unroll
      for (int mi = 0; mi < 4; ++mi)
        acc[mi][ni] = __builtin_amdgcn_mfma_i32_16x16x64_i8(av[mi], bv, acc[mi][ni], 0, 0, 0);
    }
  }

  int rowg = (lane >> 4) * 4;
#pragma unroll
  for (int mi = 0; mi < 4; ++mi)
#pragma unroll
    for (int ni = 0; ni < 4; ++ni)
#pragma unroll
      for (int v = 0; v < 4; ++v) {
        if (acc[mi][ni][v] >= 896) {
          unsigned o = (unsigned)(m0 + wr * 64 + mi * 16 + rowg + v);
          unsigned p = (unsigned)(n0 + wc * 64 + ni * 16 + fr);
          unsigned slot = atomicAdd(counter, 1u);
          if (slot < WL_CAP) wl[slot] = (o << 16) | p;
        }
      }
}

// ---- Kernel W: exact fp32 recheck (sieve AND source); scatter 0.5*w_lin[:,o] -------
__global__ void finish_fires(const float* __restrict__ x, const float* __restrict__ w1,
                             const float* __restrict__ w2, const float* __restrict__ wsrc,
                             const float* __restrict__ wlin, float* __restrict__ out,
                             const unsigned* __restrict__ counter,
                             const unsigned* __restrict__ wl) {
  unsigned n = *counter;
  if (n > WL_CAP) n = WL_CAP;
  for (unsigned i = blockIdx.x * blockDim.x + threadIdx.x; i < n;
       i += gridDim.x * blockDim.x) {
    unsigned e = wl[i];
    int o = (int)(e >> 16);
    int p = (int)(e & 0xFFFFu);
    int b = p >> 10, hw = p & 1023;
    const float* xb = x + (size_t)b * 512 * 1024 + hw;
    float s1 = 0.f, s2 = 0.f;
    for (int c = 0; c < 512; ++c) {
      if (xb[(size_t)c * 1024] >= 1.f) {
        s1 += w1[o * 512 + c] + w2[o * 512 + c];
        s2 += wsrc[o * 512 + c];
      }
    }
    if (s1 >= 4.0f && s2 >= 1.0f) {
      for (int c = 0; c < 512; ++c)
        atomicAdd(&out[((size_t)b * 512 + c) * 1024 + hw], 0.5f * wlin[c * 512 + o]);
    }
  }
}

// ---- Fallback (tiny workspace): dense fp32, one pixel per block, no scratch ------
__global__ void fallback_dense(const float* __restrict__ x, const float* __restrict__ w1,
                               const float* __restrict__ w2, const float* __restrict__ wsrc,
                               const float* __restrict__ wlin, float* __restrict__ out) {
  __shared__ float xin[512];
  __shared__ float gated[512];
  int p = blockIdx.x;
  int b = p >> 10, hw = p & 1023;
  const float* xb = x + (size_t)b * 512 * 1024 + hw;
  for (int c = threadIdx.x; c < 512; c += 256)
    xin[c] = (xb[(size_t)c * 1024] >= 1.f) ? 1.f : 0.f;
  __syncthreads();
  for (int o = threadIdx.x; o < 512; o += 256) {
    float s1 = 0.f, s2 = 0.f;
    for (int c = 0; c < 512; ++c) {
      float xv = xin[c];
      s1 += xv * (w1[o * 512 + c] + w2[o * 512 + c]);
      s2 += xv * wsrc[o * 512 + c];
    }
    gated[o] = (s1 >= 4.f && s2 >= 1.f) ? 1.f : 0.f;
  }
  __syncthreads();
  for (int c = threadIdx.x; c < 512; c += 256) {
    float a = 0.f;
    for (int o = 0; o < 512; ++o) a += gated[o] * wlin[c * 512 + o];
    out[((size_t)b * 512 + c) * 1024 + hw] = 0.5f * (a + xin[c]);
  }
}

extern "C" void kernel_launch(void* const* d_in, const int* in_sizes, int n_in,
                              void* d_out, int out_size, void* d_ws, size_t ws_size,
                              hipStream_t stream) {
  const float* x    = (const float*)d_in[0];
  const float* w1   = (const float*)d_in[1];
  const float* w2   = (const float*)d_in[2];
  const float* wsrc = (const float*)d_in[3];
  const float* wlin = (const float*)d_in[4];
  float* out = (float*)d_out;

  if (ws_size >= (size_t)8 * 1024 * 1024) {
    unsigned* counter = (unsigned*)d_ws;
    unsigned* wl = (unsigned*)((char*)d_ws + 1024);
    char* wsum_i8 = (char*)d_ws + (1u << 20);
    unsigned short* xinb16 = (unsigned short*)((char*)d_ws + (2u << 20));  // 4 MB planes

    zero_counter<<<1, 64, 0, stream>>>(counter);
    prep_wsum_i8<<<256, 256, 0, stream>>>(w1, w2, wsum_i8);
    spike_pack_direct<<<2048, 256, 0, stream>>>(x, out, xinb16);
    gemm_fire_i8<<<dim3(4, 512), 256, 0, stream>>>(wsum_i8, xinb16, counter, wl);
    finish_fires<<<dim3(32), 64, 0, stream>>>(x, w1, w2, wsrc, wlin, out, counter, wl);
  } else {
    fallback_dense<<<65536, 256, 0, stream>>>(x, w1, w2, wsrc, wlin, out);
  }
}

// Round 12
// 76.105 us; speedup vs baseline: 2.5105x; 1.0776x over previous
//
#include <hip/hip_runtime.h>
#include <hip/hip_bf16.h>

#define WL_CAP 65536u

typedef __attribute__((ext_vector_type(4))) int i32x4;
typedef __attribute__((ext_vector_type(4))) float f32x4v;
typedef __attribute__((ext_vector_type(4))) unsigned short u16x4v;

// ---------------- zero the worklist counter -----------------------------------------
__global__ void zero_counter(unsigned* c) { if (threadIdx.x == 0) *c = 0; }

// ---------------- Kernel P: wsum_i8[o][c] = clamp(rint((w1+w2)*256), -127, 127) ----
__global__ void prep_wsum_i8(const float* __restrict__ w1, const float* __restrict__ w2,
                             char* __restrict__ wsum) {
  int i = (blockIdx.x * 256 + threadIdx.x) * 4;   // 256 blocks: 262144 elems
  float4 a = *reinterpret_cast<const float4*>(w1 + i);
  float4 b = *reinterpret_cast<const float4*>(w2 + i);
  int v0 = __float2int_rn(fminf(fmaxf((a.x + b.x) * 256.f, -127.f), 127.f));
  int v1 = __float2int_rn(fminf(fmaxf((a.y + b.y) * 256.f, -127.f), 127.f));
  int v2 = __float2int_rn(fminf(fmaxf((a.z + b.z) * 256.f, -127.f), 127.f));
  int v3 = __float2int_rn(fminf(fmaxf((a.w + b.w) * 256.f, -127.f), 127.f));
  unsigned u = (v0 & 0xFF) | ((v1 & 0xFF) << 8) | ((v2 & 0xFF) << 16) | ((v3 & 0xFF) << 24);
  *reinterpret_cast<unsigned*>(wsum + i) = u;
}

// ---- Kernel E (R5 measured-best, 77.0us): batched REGULAR loads (keeps x's L3
// half-residency), NT out-stores. Block = (b, cg of 16 ch). Thread = 4 consecutive px.
// Emits ushort bitplane xinb16[cg][b*1024+px] (bit ci = spike(cg*16+ci, px)).
__global__ __launch_bounds__(256) void spike_pack_direct(const float* __restrict__ x,
                                                         float* __restrict__ out,
                                                         unsigned short* __restrict__ xinb16) {
  int t = threadIdx.x;
  int g = blockIdx.x;              // 2048 = 64 b * 32 cg
  int b = g >> 5, cg = g & 31;
  int px = t * 4;
  size_t rowbase = ((size_t)(b * 512 + cg * 16)) * 1024 + (size_t)px;

  f32x4v v[16];
#pragma unroll
  for (int ci = 0; ci < 16; ++ci)
    v[ci] = *reinterpret_cast<const f32x4v*>(x + rowbase + (size_t)ci * 1024);

  unsigned u0 = 0, u1 = 0, u2 = 0, u3 = 0;
#pragma unroll
  for (int ci = 0; ci < 16; ++ci) {
    unsigned s0 = (v[ci].x >= 1.f) ? 1u : 0u;
    unsigned s1 = (v[ci].y >= 1.f) ? 1u : 0u;
    unsigned s2 = (v[ci].z >= 1.f) ? 1u : 0u;
    unsigned s3 = (v[ci].w >= 1.f) ? 1u : 0u;
    f32x4v ov;
    ov.x = 0.5f * (float)s0; ov.y = 0.5f * (float)s1;
    ov.z = 0.5f * (float)s2; ov.w = 0.5f * (float)s3;
    __builtin_nontemporal_store(ov,
        reinterpret_cast<f32x4v*>(out + rowbase + (size_t)ci * 1024));
    u0 |= s0 << ci; u1 |= s1 << ci; u2 |= s2 << ci; u3 |= s3 << ci;
  }
  u16x4v o;
  o.x = (unsigned short)u0; o.y = (unsigned short)u1;
  o.z = (unsigned short)u2; o.w = (unsigned short)u3;
  *reinterpret_cast<u16x4v*>(xinb16 + (size_t)cg * 65536 + (size_t)(b * 1024 + px)) = o;
}

// ---- Kernel G (R5): i8 fire-detect GEMM, bbits preloaded from bitplanes ----------
__global__ __launch_bounds__(256) void gemm_fire_i8(const char* __restrict__ wsum,
                                                    const unsigned short* __restrict__ xinb16,
                                                    unsigned* __restrict__ counter,
                                                    unsigned* __restrict__ wl) {
  __shared__ char As[128 * 512];   // 64 KB
  int m0 = blockIdx.x * 128;
  int n0 = blockIdx.y * 128;
  int t = threadIdx.x;
  int lane = t & 63;
  int wv = t >> 6;
  int wr = wv >> 1, wc = wv & 1;
  int fr = lane & 15;
  int kgrp = lane >> 4;

#pragma unroll
  for (int i = 0; i < 16; ++i) {
    int idx = t + i * 256;
    int row = idx >> 5;
    int col16 = (idx & 31) * 16;
    int scol = col16 ^ ((row & 7) << 4);
    const char* ga = wsum + (size_t)(m0 + row) * 512 + scol;
    __builtin_amdgcn_global_load_lds((const __attribute__((address_space(1))) void*)ga,
                                     (__attribute__((address_space(3))) void*)(As + idx * 16),
                                     16, 0, 0);
  }

  unsigned short bbits[4][8];
#pragma unroll
  for (int ni = 0; ni < 4; ++ni) {
    int prow = n0 + wc * 64 + ni * 16 + fr;
#pragma unroll
    for (int kt = 0; kt < 8; ++kt)
      bbits[ni][kt] = xinb16[(size_t)(kt * 4 + kgrp) * 65536 + prow];
  }

  i32x4 acc[4][4];
#pragma unroll
  for (int i = 0; i < 4; ++i)
#pragma unroll
    for (int j = 0; j < 4; ++j) acc[i][j] = (i32x4){0, 0, 0, 0};

  __syncthreads();

#pragma unroll
  for (int kt = 0; kt < 8; ++kt) {
    i32x4 av[4];
#pragma unroll
    for (int mi = 0; mi < 4; ++mi) {
      int row = wr * 64 + mi * 16 + fr;
      int col = (kt * 64 + kgrp * 16) ^ ((row & 7) << 4);
      av[mi] = *reinterpret_cast<const i32x4*>(&As[row * 512 + col]);
    }
#pragma unroll
    for (int ni = 0; ni < 4; ++ni) {
      unsigned s = bbits[ni][kt];
      i32x4 bv;
      bv[0] = (int)((((s      ) & 0xFu) * 0x00204081u) & 0x01010101u);
      bv[1] = (int)((((s >>  4) & 0xFu) * 0x00204081u) & 0x01010101u);
      bv[2] = (int)((((s >>  8) & 0xFu) * 0x00204081u) & 0x01010101u);
      bv[3] = (int)((((s >> 12) & 0xFu) * 0x00204081u) & 0x01010101u);
#pragma unroll
      for (int mi = 0; mi < 4; ++mi)
        acc[mi][ni] = __builtin_amdgcn_mfma_i32_16x16x64_i8(av[mi], bv, acc[mi][ni], 0, 0, 0);
    }
  }

  int rowg = (lane >> 4) * 4;
#pragma unroll
  for (int mi = 0; mi < 4; ++mi)
#pragma unroll
    for (int ni = 0; ni < 4; ++ni)
#pragma unroll
      for (int v = 0; v < 4; ++v) {
        if (acc[mi][ni][v] >= 896) {
          unsigned o = (unsigned)(m0 + wr * 64 + mi * 16 + rowg + v);
          unsigned p = (unsigned)(n0 + wc * 64 + ni * 16 + fr);
          unsigned slot = atomicAdd(counter, 1u);
          if (slot < WL_CAP) wl[slot] = (o << 16) | p;
        }
      }
}

// ---- Kernel W: exact fp32 recheck (sieve AND source); scatter 0.5*w_lin[:,o] -------
__global__ void finish_fires(const float* __restrict__ x, const float* __restrict__ w1,
                             const float* __restrict__ w2, const float* __restrict__ wsrc,
                             const float* __restrict__ wlin, float* __restrict__ out,
                             const unsigned* __restrict__ counter,
                             const unsigned* __restrict__ wl) {
  unsigned n = *counter;
  if (n > WL_CAP) n = WL_CAP;
  for (unsigned i = blockIdx.x * blockDim.x + threadIdx.x; i < n;
       i += gridDim.x * blockDim.x) {
    unsigned e = wl[i];
    int o = (int)(e >> 16);
    int p = (int)(e & 0xFFFFu);
    int b = p >> 10, hw = p & 1023;
    const float* xb = x + (size_t)b * 512 * 1024 + hw;
    float s1 = 0.f, s2 = 0.f;
    for (int c = 0; c < 512; ++c) {
      if (xb[(size_t)c * 1024] >= 1.f) {
        s1 += w1[o * 512 + c] + w2[o * 512 + c];
        s2 += wsrc[o * 512 + c];
      }
    }
    if (s1 >= 4.0f && s2 >= 1.0f) {
      for (int c = 0; c < 512; ++c)
        atomicAdd(&out[((size_t)b * 512 + c) * 1024 + hw], 0.5f * wlin[c * 512 + o]);
    }
  }
}

// ---- Fallback (tiny workspace): dense fp32, one pixel per block, no scratch ------
__global__ void fallback_dense(const float* __restrict__ x, const float* __restrict__ w1,
                               const float* __restrict__ w2, const float* __restrict__ wsrc,
                               const float* __restrict__ wlin, float* __restrict__ out) {
  __shared__ float xin[512];
  __shared__ float gated[512];
  int p = blockIdx.x;
  int b = p >> 10, hw = p & 1023;
  const float* xb = x + (size_t)b * 512 * 1024 + hw;
  for (int c = threadIdx.x; c < 512; c += 256)
    xin[c] = (xb[(size_t)c * 1024] >= 1.f) ? 1.f : 0.f;
  __syncthreads();
  for (int o = threadIdx.x; o < 512; o += 256) {
    float s1 = 0.f, s2 = 0.f;
    for (int c = 0; c < 512; ++c) {
      float xv = xin[c];
      s1 += xv * (w1[o * 512 + c] + w2[o * 512 + c]);
      s2 += xv * wsrc[o * 512 + c];
    }
    gated[o] = (s1 >= 4.f && s2 >= 1.f) ? 1.f : 0.f;
  }
  __syncthreads();
  for (int c = threadIdx.x; c < 512; c += 256) {
    float a = 0.f;
    for (int o = 0; o < 512; ++o) a += gated[o] * wlin[c * 512 + o];
    out[((size_t)b * 512 + c) * 1024 + hw] = 0.5f * (a + xin[c]);
  }
}

extern "C" void kernel_launch(void* const* d_in, const int* in_sizes, int n_in,
                              void* d_out, int out_size, void* d_ws, size_t ws_size,
                              hipStream_t stream) {
  const float* x    = (const float*)d_in[0];
  const float* w1   = (const float*)d_in[1];
  const float* w2   = (const float*)d_in[2];
  const float* wsrc = (const float*)d_in[3];
  const float* wlin = (const float*)d_in[4];
  float* out = (float*)d_out;

  if (ws_size >= (size_t)8 * 1024 * 1024) {
    unsigned* counter = (unsigned*)d_ws;
    unsigned* wl = (unsigned*)((char*)d_ws + 1024);
    char* wsum_i8 = (char*)d_ws + (1u << 20);
    unsigned short* xinb16 = (unsigned short*)((char*)d_ws + (2u << 20));  // 4 MB planes

    zero_counter<<<1, 64, 0, stream>>>(counter);
    prep_wsum_i8<<<256, 256, 0, stream>>>(w1, w2, wsum_i8);
    spike_pack_direct<<<2048, 256, 0, stream>>>(x, out, xinb16);
    gemm_fire_i8<<<dim3(4, 512), 256, 0, stream>>>(wsum_i8, xinb16, counter, wl);
    finish_fires<<<dim3(32), 64, 0, stream>>>(x, w1, w2, wsrc, wlin, out, counter, wl);
  } else {
    fallback_dense<<<65536, 256, 0, stream>>>(x, w1, w2, wsrc, wlin, out);
  }
}